// Round 3
// baseline (79.002 us; speedup 1.0000x reference)
//
#include <hip/hip_runtime.h>

// S4D kernel generation: K[h,l] = 2*Re( sum_n Ceff[h,n] * exp(dtA[h,n]*l) )
//   dtA = A*dt, A = -exp(log_A_real) + i*A_imag, dt = exp(log_dt)
//   Ceff = C * (exp(dtA)-1)/A
//
// Structure: one block per h (grid=1024, block=256). Thread t owns the 16
// coalesced outputs l = t + 256*j.
//   * u_j = 2*Re(Ceff * exp(dtA*(t+256j))) obeys the real 2nd-order
//     recurrence u_j = 2Re(w)*u_{j-1} - |w|^2*u_{j-2}, w = exp(256*dtA).
//   * n packed in pairs as float2 ext-vectors -> v_pk_fma_f32.
//   * R3: TWO independent recurrence chains (pairs m and m+8) interleaved in
//     one loop iteration — the serial u-chain (~8-10 cyc/iter latency vs
//     6 cyc issue) can't be hidden at 4 waves/SIMD with a single chain.
//   * Seed phases reduced mod 1 revolution in fp64, hardware v_sin/v_cos.

#define HD   1024
#define NS   32
#define LL   4096
#define BLK  256
#define NJ   (LL / BLK)   // 16

typedef float v2 __attribute__((ext_vector_type(2)));

__global__ __launch_bounds__(BLK) void s4d_kernel(
    const float* __restrict__ log_dt,
    const float* __restrict__ C_ri,
    const float* __restrict__ log_A_real,
    const float* __restrict__ A_imag,
    float* __restrict__ K)
{
    const int h   = blockIdx.x;
    const int tid = threadIdx.x;

    // Pair layout: slot (n&15)*2 + (n>>4), so v2-pair np holds n=np and n=np+16.
    __shared__ v2 s_wr[NS / 2], s_wi[NS / 2];     // w = exp(256*dtA)
    __shared__ v2 s_q[NS / 2];                    // |w|^2
    __shared__ v2 s_c2r[NS / 2], s_c2i[NS / 2];   // 2*Ceff
    __shared__ v2 s_al2[NS / 2];                  // Re(dtA)*log2(e)
    __shared__ double s_rb[NS];                   // Im(dtA)/(2pi), plain index n

    const double TWO_PI     = 6.283185307179586;
    const double INV_TWO_PI = 0.15915494309189535;
    const float  TWO_PI_F   = 6.2831853f;

    if (tid < NS) {
        const int   n   = tid;
        const int   sl  = ((n & 15) << 1) | (n >> 4);
        const float dt  = expf(log_dt[h]);
        const float ar  = -expf(log_A_real[h * NS + n]);   // Re(A)
        const float ai  = A_imag[h * NS + n];              // Im(A)
        const float a   = ar * dt;                         // Re(dtA)
        const double bd = (double)ai * (double)dt;         // Im(dtA)
        const float b   = (float)bd;

        // exp(dtA) - 1
        const float e = expf(a);
        float sb, cb;
        sincosf(b, &sb, &cb);
        const float er = fmaf(e, cb, -1.0f);
        const float ei = e * sb;

        // (er + i*ei) / (ar + i*ai)
        const float den = fmaf(ar, ar, ai * ai);
        const float inv = 1.0f / den;
        const float fr  = fmaf(er, ar,  ei * ai) * inv;
        const float fi  = fmaf(ei, ar, -er * ai) * inv;

        const float Cr = C_ri[(h * NS + n) * 2 + 0];
        const float Ci = C_ri[(h * NS + n) * 2 + 1];
        ((float*)s_c2r)[sl] = 2.0f * fmaf(Cr, fr, -Ci * fi);
        ((float*)s_c2i)[sl] = 2.0f * fmaf(Cr, fi,  Ci * fr);

        // w = exp(256*dtA), phase reduced mod 2pi in fp64
        double ph = bd * 256.0;
        ph -= floor(ph * INV_TWO_PI) * TWO_PI;
        float sw, cw;
        sincosf((float)ph, &sw, &cw);
        const float e256 = expf(a * 256.0f);
        ((float*)s_wr)[sl]  = e256 * cw;
        ((float*)s_wi)[sl]  = e256 * sw;
        ((float*)s_q)[sl]   = e256 * e256;
        ((float*)s_al2)[sl] = a * 1.4426950408889634f;
        s_rb[n] = bd * INV_TWO_PI;   // revolutions per unit l
    }
    __syncthreads();

    v2 acc[NJ];
#pragma unroll
    for (int j = 0; j < NJ; ++j) acc[j] = (v2)(0.0f);

    const float  t  = (float)tid;
    const double td = (double)tid;

    for (int m = 0; m < NS / 4; ++m) {        // chains A = m, B = m + 8
        const int mA = m, mB = m + 8;

        // ---- seeds, chain A ----
        const v2 al2A = s_al2[mA];
        v2 magA;
        magA.x = __builtin_amdgcn_exp2f(al2A.x * t);
        magA.y = __builtin_amdgcn_exp2f(al2A.y * t);
        double rA0 = s_rb[mA] * td;        rA0 -= floor(rA0);
        double rA1 = s_rb[mA + 16] * td;   rA1 -= floor(rA1);
        const float fA0 = (float)rA0 * TWO_PI_F;
        const float fA1 = (float)rA1 * TWO_PI_F;
        v2 zrA, ziA;
        zrA.x = magA.x * __cosf(fA0);  zrA.y = magA.y * __cosf(fA1);
        ziA.x = magA.x * __sinf(fA0);  ziA.y = magA.y * __sinf(fA1);

        // ---- seeds, chain B ----
        const v2 al2B = s_al2[mB];
        v2 magB;
        magB.x = __builtin_amdgcn_exp2f(al2B.x * t);
        magB.y = __builtin_amdgcn_exp2f(al2B.y * t);
        double rB0 = s_rb[mB] * td;        rB0 -= floor(rB0);
        double rB1 = s_rb[mB + 16] * td;   rB1 -= floor(rB1);
        const float fB0 = (float)rB0 * TWO_PI_F;
        const float fB1 = (float)rB1 * TWO_PI_F;
        v2 zrB, ziB;
        zrB.x = magB.x * __cosf(fB0);  zrB.y = magB.y * __cosf(fB1);
        ziB.x = magB.x * __sinf(fB0);  ziB.y = magB.y * __sinf(fB1);

        // ---- u0, u1 for both chains ----
        const v2 wrA = s_wr[mA], wiA = s_wi[mA], qA = s_q[mA];
        const v2 wrB = s_wr[mB], wiB = s_wi[mB], qB = s_q[mB];
        const v2 c2rA = s_c2r[mA], c2iA = s_c2i[mA];
        const v2 c2rB = s_c2r[mB], c2iB = s_c2i[mB];

        v2 u0A = c2rA * zrA - c2iA * ziA;
        v2 u0B = c2rB * zrB - c2iB * ziB;
        v2 zwrA = zrA * wrA - ziA * wiA;
        v2 zwiA = zrA * wiA + ziA * wrA;
        v2 zwrB = zrB * wrB - ziB * wiB;
        v2 zwiB = zrB * wiB + ziB * wrB;
        v2 u1A = c2rA * zwrA - c2iA * zwiA;
        v2 u1B = c2rB * zwrB - c2iB * zwiB;
        const v2 pA = wrA + wrA;
        const v2 pB = wrB + wrB;

        acc[0] += u0A;  acc[0] += u0B;
        acc[1] += u1A;  acc[1] += u1B;
#pragma unroll
        for (int j = 2; j < NJ; ++j) {
            const v2 uA = pA * u1A - qA * u0A;
            const v2 uB = pB * u1B - qB * u0B;
            acc[j] += uA;
            acc[j] += uB;
            u0A = u1A;  u1A = uA;
            u0B = u1B;  u1B = uB;
        }
    }

    float* out = K + h * LL + tid;
#pragma unroll
    for (int j = 0; j < NJ; ++j) out[j * BLK] = acc[j].x + acc[j].y;
}

extern "C" void kernel_launch(void* const* d_in, const int* in_sizes, int n_in,
                              void* d_out, int out_size, void* d_ws, size_t ws_size,
                              hipStream_t stream) {
    // d_in[0] = L (int scalar, == 4096, hard-coded)
    const float* log_dt     = (const float*)d_in[1];
    const float* C_ri       = (const float*)d_in[2];
    const float* log_A_real = (const float*)d_in[3];
    const float* A_imag     = (const float*)d_in[4];
    float* K = (float*)d_out;

    s4d_kernel<<<dim3(HD), dim3(BLK), 0, stream>>>(log_dt, C_ri, log_A_real, A_imag, K);
}